// Round 10
// baseline (396.130 us; speedup 1.0000x reference)
//
#include <hip/hip_runtime.h>
#include <hip/hip_cooperative_groups.h>
#include <stdint.h>

namespace cg = cooperative_groups;

// B=131072 rows, K=IN=256, N=OUT=256.
// temp = act @ weight.T (exact int32, |t| < 2^22); r = max|temp|;
// bw = ceil(log2(max(r,1))) (0 if r<=1); shift = bw-7;
// shift>0 ? round_shift(temp,shift) clipped to [-127,127] : int8-wrap(temp)
// exp_out = exp_in + weight_exp + max(shift,0)  (int16 semantics)
// Harness reads d_out as INT32: [B*N values, 1 exp scalar].
//
// v11: ONE cooperative kernel; act8 lives in LDS across a grid sync.
//  - v10 post-mortem: ours ~110us vs ~48us floor; excess = act8 global
//    round-trip + shallow-in-flight streaming (2KB/CU outstanding vs 9KB
//    needed at ~900cy HBM latency).
//  - 256 blocks (1/CU) x 1024 thr; block owns 512 rows. Stage fp32->i8
//    into LDS (144 KB, ASTR=288: 4-way max on ds_read_b128). Phase 1:
//    GEMM (B 16B/lane direct from L2-hot wi8) -> abs-max -> atomicMax.
//    grid.sync(). Phase 2: recompute GEMM from LDS (MFMA ~7% util ->
//    recompute ~free), quantize in regs, nt-store out.
//  - HBM/iter: 134 R + 134 W only. No act8 global, no raw-temp.
//  - acc per quarter = iv4[2][4] (32 regs, proven non-spill).

#define M_ROWS 131072
#define NK 256
#define BLK_ROWS 512
#define ASTR 288          // LDS row stride bytes

typedef __attribute__((ext_vector_type(4))) int iv4;
typedef __attribute__((ext_vector_type(4))) float fv4;
typedef __attribute__((ext_vector_type(4))) unsigned int u32x4;

// D = A*B + C, 16x16 K=64, signed i8 inputs, i32 accum (exact).
__device__ __forceinline__ iv4 mfma_i8(iv4 a, iv4 b, iv4 c) {
  asm("v_mfma_i32_16x16x64_i8 %0, %1, %2, %0" : "+v"(c) : "v"(a), "v"(b));
  return c;
}

// 4 int-valued floats -> 4 packed signed bytes (two's complement).
__device__ __forceinline__ unsigned int pack_i8x4(float a, float b, float c,
                                                  float d) {
  return ((unsigned int)(int)a & 0xFFu) | (((unsigned int)(int)b & 0xFFu) << 8) |
         (((unsigned int)(int)c & 0xFFu) << 16) | ((unsigned int)(int)d << 24);
}

// Prepass: weight fp32 -> i8 (64 KB; L2/LLC-resident). Zeroes gmax.
__global__ void wconv(const float* __restrict__ w, unsigned char* __restrict__ wi8,
                      int* __restrict__ gmax) {
  if (blockIdx.x == 0 && threadIdx.x == 0) *gmax = 0;
  const int i = blockIdx.x * 256 + threadIdx.x;
  const fv4 f = ((const fv4*)w)[i];
  ((unsigned int*)wi8)[i] = pack_i8x4(f.x, f.y, f.z, f.w);
}

__global__ __launch_bounds__(1024, 4) void fused(
    const float* __restrict__ act, const unsigned char* __restrict__ wi8,
    int* __restrict__ out, int* __restrict__ gmax,
    const int* __restrict__ exp_in, const int* __restrict__ wexp)
{
  __shared__ __align__(16) unsigned char As[BLK_ROWS * ASTR];  // 147456 B
  __shared__ int smax;
  const int tid = threadIdx.x;
  if (tid == 0) smax = 0;

  const size_t rowbase = (size_t)blockIdx.x * BLK_ROWS;

  // Stage 512 rows fp32 -> i8 into LDS. 8192 16B-chunks / 1024 thr.
#pragma unroll 2
  for (int it = 0; it < 8; ++it) {
    const int c   = it * 1024 + tid;
    const int row = c >> 4;               // 0..511
    const int kc  = (c & 15) << 4;        // byte (=elem) offset
    const float* p = act + (rowbase + row) * NK + kc;
    const fv4 f0 = ((const fv4*)p)[0];
    const fv4 f1 = ((const fv4*)p)[1];
    const fv4 f2 = ((const fv4*)p)[2];
    const fv4 f3 = ((const fv4*)p)[3];
    u32x4 v;
    v.x = pack_i8x4(f0.x, f0.y, f0.z, f0.w);
    v.y = pack_i8x4(f1.x, f1.y, f1.z, f1.w);
    v.z = pack_i8x4(f2.x, f2.y, f2.z, f2.w);
    v.w = pack_i8x4(f3.x, f3.y, f3.z, f3.w);
    *(u32x4*)&As[row * ASTR + kc] = v;
  }
  __syncthreads();

  const int lane = tid & 63;
  const int w    = tid >> 6;        // 0..15; wave owns rows w*32..+31
  const int lm   = lane & 15;
  const int lk   = lane >> 4;

  // ---- Phase 1: GEMM -> abs-max ----
  int imax = 0;
#pragma unroll
  for (int ni4 = 0; ni4 < 4; ++ni4) {   // output col quarter (64 cols)
    iv4 acc[2][4] = {};
#pragma unroll
    for (int kk = 0; kk < 4; ++kk) {    // K = 4 x 64
      iv4 af[2], bf[4];
#pragma unroll
      for (int mi = 0; mi < 2; ++mi)
        af[mi] = *(const iv4*)&As[(w * 32 + mi * 16 + lm) * ASTR + kk * 64 + lk * 16];
#pragma unroll
      for (int ni = 0; ni < 4; ++ni)
        bf[ni] = *(const iv4*)(wi8 +
            (size_t)(ni4 * 64 + ni * 16 + lm) * NK + kk * 64 + lk * 16);
#pragma unroll
      for (int mi = 0; mi < 2; ++mi)
#pragma unroll
        for (int ni = 0; ni < 4; ++ni)
          acc[mi][ni] = mfma_i8(af[mi], bf[ni], acc[mi][ni]);
    }
#pragma unroll
    for (int mi = 0; mi < 2; ++mi)
#pragma unroll
      for (int ni = 0; ni < 4; ++ni)
#pragma unroll
        for (int r = 0; r < 4; ++r) {
          const int ti = acc[mi][ni][r];
          const int a = ti < 0 ? -ti : ti;
          imax = a > imax ? a : imax;
        }
  }
#pragma unroll
  for (int off = 32; off; off >>= 1) {
    const int o = __shfl_xor(imax, off, 64);
    imax = o > imax ? o : imax;
  }
  if (lane == 0) atomicMax(&smax, imax);
  __syncthreads();
  if (tid == 0) atomicMax(gmax, smax);
  __threadfence();

  cg::this_grid().sync();

  const int rmax = __hip_atomic_load(gmax, __ATOMIC_RELAXED,
                                     __HIP_MEMORY_SCOPE_AGENT);
  const int bw = (rmax <= 1) ? 0 : (32 - __clz(rmax - 1));   // ceil(log2(r))
  const int shift = bw - 7;
  const bool pos = shift > 0;
  const int s = shift < 1 ? 1 : shift;

  // ---- Phase 2: recompute GEMM from LDS, quantize, store ----
#pragma unroll
  for (int ni4 = 0; ni4 < 4; ++ni4) {
    iv4 acc[2][4] = {};
#pragma unroll
    for (int kk = 0; kk < 4; ++kk) {
      iv4 af[2], bf[4];
#pragma unroll
      for (int mi = 0; mi < 2; ++mi)
        af[mi] = *(const iv4*)&As[(w * 32 + mi * 16 + lm) * ASTR + kk * 64 + lk * 16];
#pragma unroll
      for (int ni = 0; ni < 4; ++ni)
        bf[ni] = *(const iv4*)(wi8 +
            (size_t)(ni4 * 64 + ni * 16 + lm) * NK + kk * 64 + lk * 16);
#pragma unroll
      for (int mi = 0; mi < 2; ++mi)
#pragma unroll
        for (int ni = 0; ni < 4; ++ni)
          acc[mi][ni] = mfma_i8(af[mi], bf[ni], acc[mi][ni]);
    }
#pragma unroll
    for (int mi = 0; mi < 2; ++mi)
#pragma unroll
      for (int ni = 0; ni < 4; ++ni)
#pragma unroll
        for (int r = 0; r < 4; ++r) {
          const int ti = acc[mi][ni][r];
          int q;
          if (pos) {
            const int rt = ti >> s;                       // floor(t / 2^s)
            const int dec = (ti - (rt << s)) >> (s - 1);  // {0,1}
            q = rt + dec;
            q = q > 127 ? 127 : (q < -127 ? -127 : q);
          } else {
            q = (int)(signed char)(ti & 0xFF);            // int8 wrap
          }
          const size_t m = rowbase + w * 32 + mi * 16 + lk * 4 + r;
          const int n = ni4 * 64 + ni * 16 + lm;
          __builtin_nontemporal_store(q, &out[m * NK + n]);
        }
  }

  if (blockIdx.x == 0 && tid == 0) {
    const int e = exp_in[0] + wexp[0] + (pos ? shift : 0);
    out[(size_t)M_ROWS * NK] = (int)(short)e;
  }
}

extern "C" void kernel_launch(void* const* d_in, const int* in_sizes, int n_in,
                              void* d_out, int out_size, void* d_ws, size_t ws_size,
                              hipStream_t stream) {
  const float* act   = (const float*)d_in[0];
  const int* exp_in  = (const int*)d_in[1];
  const float* wgt   = (const float*)d_in[2];
  const int* wexp    = (const int*)d_in[3];
  int* gmax           = (int*)d_ws;
  unsigned char* wi8  = (unsigned char*)d_ws + 4096;        // 64 KB

  wconv<<<dim3(64), dim3(256), 0, stream>>>(wgt, wi8, gmax);

  int* outp = (int*)d_out;
  void* args[] = {(void*)&act, (void*)&wi8, (void*)&outp,
                  (void*)&gmax, (void*)&exp_in, (void*)&wexp};
  (void)hipLaunchCooperativeKernel((void*)fused, dim3(M_ROWS / BLK_ROWS),
                                   dim3(1024), args, 0, stream);
}